// Round 1
// baseline (1575.095 us; speedup 1.0000x reference)
//
#include <hip/hip_runtime.h>

#define NN  100000
#define NNZq 3200000
#define NE  1000000

typedef float f32x4 __attribute__((ext_vector_type(4)));
typedef unsigned short ushort_t;
typedef ushort_t us4 __attribute__((ext_vector_type(4)));
typedef ushort_t us8 __attribute__((ext_vector_type(8)));
typedef __bf16 bf8 __attribute__((ext_vector_type(8)));

__device__ __forceinline__ ushort_t f2bf(float f){
  unsigned u = __builtin_bit_cast(unsigned, f);
  u += 0x7FFFu + ((u >> 16) & 1u);
  return (ushort_t)(u >> 16);
}
__device__ __forceinline__ float bf2f(ushort_t s){
  unsigned u = ((unsigned)s) << 16;
  return __builtin_bit_cast(float, u);
}
__device__ __forceinline__ float sigm(float x){ return 1.f/(1.f + __expf(-x)); }
__device__ __forceinline__ float tanh_f(float x){ return 1.f - 2.f/(1.f + __expf(2.f*x)); }

__device__ __forceinline__ f32x4 MFMA(bf8 a, bf8 b, f32x4 c){
  return __builtin_amdgcn_mfma_f32_16x16x32_bf16(a, b, c, 0, 0, 0);
}

// ---------------- weight prep: transposed bf16 hi/lo copies ----------------
__global__ __launch_bounds__(256) void k_prep(
    const float* __restrict__ W_in, const float* __restrict__ W_gate,
    const float* __restrict__ W_out, const float* __restrict__ W_e1,
    ushort_t* __restrict__ Wt_in, ushort_t* __restrict__ Wgt,
    ushort_t* __restrict__ Wot, ushort_t* __restrict__ Wt_e1)
{
  int tid = blockIdx.x * 256 + threadIdx.x;
  int stride = gridDim.x * 256;
  // Wt_in: [64][512] (hi 0..255 | lo 256..511), col-major-transposed
  for (int i = tid; i < 64*256; i += stride){
    int c = i >> 8, k = i & 255;
    float f = W_in[k*64 + c];
    ushort_t hi = f2bf(f); ushort_t lo = f2bf(f - bf2f(hi));
    Wt_in[c*512 + k] = hi; Wt_in[c*512 + 256 + k] = lo;
  }
  // Wgt: [2][64][256] (hi 128 | lo 128)
  for (int i = tid; i < 2*64*128; i += stride){
    int hop = i >> 13, r = i & 8191; int c = r >> 7, k = r & 127;
    float f = W_gate[hop*8192 + k*64 + c];
    ushort_t hi = f2bf(f); ushort_t lo = f2bf(f - bf2f(hi));
    Wgt[hop*16384 + c*256 + k] = hi; Wgt[hop*16384 + c*256 + 128 + k] = lo;
  }
  // Wot: [2][64][128] (hi 64 | lo 64)
  for (int i = tid; i < 2*64*64; i += stride){
    int hop = i >> 12, r = i & 4095; int c = r >> 6, k = r & 63;
    float f = W_out[hop*4096 + k*64 + c];
    ushort_t hi = f2bf(f); ushort_t lo = f2bf(f - bf2f(hi));
    Wot[hop*8192 + c*128 + k] = hi; Wot[hop*8192 + c*128 + 64 + k] = lo;
  }
  // Wt_e1: [64][288] bf16 hi only, zero-pad k>=272
  for (int i = tid; i < 64*288; i += stride){
    int c = i / 288, k = i - c*288;
    float f = (k < 272) ? W_e1[k*64 + c] : 0.f;
    Wt_e1[c*288 + k] = f2bf(f);
  }
}

// ---------------- h = tanh(x @ W_in + b), split-bf16 MFMA (3 terms, K'=768) ----------------
__global__ __launch_bounds__(256) void k_embed(
    const float* __restrict__ x, const ushort_t* __restrict__ Wt,
    const float* __restrict__ b_in, float* __restrict__ h)
{
  __shared__ ushort_t Al[64][520];   // hi 0..255 | lo 256..511 | pad
  __shared__ ushort_t Bl[64][520];
  int t = threadIdx.x;
  int r0 = blockIdx.x * 64;
  const uint4* W4 = (const uint4*)Wt;
  #pragma unroll
  for (int n = 0; n < 16; n++){
    int i = t + n*256;
    int row = i >> 6, kc = i & 63;
    *(uint4*)&Bl[row][kc*8] = W4[i];
  }
  #pragma unroll
  for (int n = 0; n < 16; n++){
    int i = t + n*256;
    int row = i >> 6, kc = i & 63;
    float4 vv = make_float4(0.f,0.f,0.f,0.f);
    if (r0 + row < NN) vv = *(const float4*)(x + (r0+row)*256 + kc*4);
    float fv[4] = {vv.x, vv.y, vv.z, vv.w};
    us4 hi, lo;
    #pragma unroll
    for (int j = 0; j < 4; j++){
      ushort_t hh = f2bf(fv[j]); hi[j] = hh; lo[j] = f2bf(fv[j] - bf2f(hh));
    }
    *(us4*)&Al[row][kc*4] = hi;
    *(us4*)&Al[row][256 + kc*4] = lo;
  }
  __syncthreads();
  int l = t & 63, w = t >> 6;
  int lr = l & 15, lg = l >> 4;
  int wm = w >> 1, wn = w & 1;
  f32x4 z = {0.f,0.f,0.f,0.f};
  f32x4 acc[4] = {z,z,z,z};
  #pragma unroll
  for (int ks = 0; ks < 24; ks++){
    int aoff = (ks < 8) ? ks*32 : (ks < 16) ? 256 + (ks-8)*32 : (ks-16)*32;
    int boff = (ks < 16) ? (ks & 7)*32 : 256 + (ks-16)*32;
    bf8 a0 = *(const bf8*)&Al[32*wm      + lr][aoff + 8*lg];
    bf8 a1 = *(const bf8*)&Al[32*wm + 16 + lr][aoff + 8*lg];
    bf8 b0 = *(const bf8*)&Bl[32*wn      + lr][boff + 8*lg];
    bf8 b1 = *(const bf8*)&Bl[32*wn + 16 + lr][boff + 8*lg];
    acc[0] = MFMA(a0,b0,acc[0]);
    acc[1] = MFMA(a0,b1,acc[1]);
    acc[2] = MFMA(a1,b0,acc[2]);
    acc[3] = MFMA(a1,b1,acc[3]);
  }
  #pragma unroll
  for (int am = 0; am < 2; am++)
  #pragma unroll
  for (int bn = 0; bn < 2; bn++){
    f32x4 A = acc[am*2 + bn];
    int col = 32*wn + 16*bn + lr;
    float bi = b_in[col];
    #pragma unroll
    for (int reg = 0; reg < 4; reg++){
      int row = 32*wm + 16*am + 4*lg + reg;
      if (r0 + row < NN) h[(r0+row)*64 + col] = tanh_f(A[reg] + bi);
    }
  }
}

// ---------------- CSR build ----------------
__global__ __launch_bounds__(256) void k_hist(const int* __restrict__ rows, int* __restrict__ cnt){
  int i = blockIdx.x*256 + threadIdx.x;
  atomicAdd(&cnt[rows[i]], 1);
}

__global__ __launch_bounds__(256) void k_scan1(const int* __restrict__ cnt, int* __restrict__ rp, int* __restrict__ bs){
  __shared__ int sh[256];
  int t = threadIdx.x; int i = blockIdx.x*256 + t;
  int v = (i < NN) ? cnt[i] : 0;
  sh[t] = v; __syncthreads();
  for (int off = 1; off < 256; off <<= 1){
    int xx = (t >= off) ? sh[t-off] : 0;
    __syncthreads();
    sh[t] += xx;
    __syncthreads();
  }
  if (i < NN) rp[i] = sh[t] - v;
  if (t == 255) bs[blockIdx.x] = sh[255];
}

__global__ __launch_bounds__(512) void k_scan2(int* __restrict__ bs, int nb){
  __shared__ int sh[512];
  int t = threadIdx.x;
  int v = (t < nb) ? bs[t] : 0;
  sh[t] = v; __syncthreads();
  for (int off = 1; off < 512; off <<= 1){
    int xx = (t >= off) ? sh[t-off] : 0;
    __syncthreads();
    sh[t] += xx;
    __syncthreads();
  }
  if (t < nb) bs[t] = sh[t] - v;
}

__global__ __launch_bounds__(256) void k_scan3(int* __restrict__ rp, const int* __restrict__ bs, int* __restrict__ cur){
  int i = blockIdx.x*256 + threadIdx.x;
  if (i < NN){
    int vv = rp[i] + bs[blockIdx.x];
    rp[i] = vv; cur[i] = vv;
  }
  if (i == 0) rp[NN] = NNZq;
}

__global__ __launch_bounds__(256) void k_scatter(const int* __restrict__ rows, const int* __restrict__ cols,
    const float* __restrict__ vals, int* __restrict__ cur, uint2* __restrict__ csr){
  int i = blockIdx.x*256 + threadIdx.x;
  int r = rows[i];
  int pp = atomicAdd(&cur[r], 1);
  uint2 e; e.x = (unsigned)cols[i]; e.y = __builtin_bit_cast(unsigned, vals[i]);
  csr[pp] = e;
}

// ---------------- SpMM: one wave per row, fp32 gather+accumulate ----------------
__global__ __launch_bounds__(256) void k_spmm(
    const int* __restrict__ rowptr, const uint2* __restrict__ csr,
    const float* __restrict__ h, float* __restrict__ out)
{
  int w = blockIdx.x * 4 + (threadIdx.x >> 6);
  int l = threadIdx.x & 63;
  int s = rowptr[w], e = rowptr[w+1];
  float acc = 0.f;
  int i = s;
  for (; i + 4 <= e; i += 4){
    uint2 p0 = csr[i], p1 = csr[i+1], p2 = csr[i+2], p3 = csr[i+3];
    float g0 = h[p0.x*64 + l];
    float g1 = h[p1.x*64 + l];
    float g2 = h[p2.x*64 + l];
    float g3 = h[p3.x*64 + l];
    acc += __builtin_bit_cast(float, p0.y) * g0;
    acc += __builtin_bit_cast(float, p1.y) * g1;
    acc += __builtin_bit_cast(float, p2.y) * g2;
    acc += __builtin_bit_cast(float, p3.y) * g3;
  }
  for (; i < e; i++){
    uint2 p = csr[i];
    acc += __builtin_bit_cast(float, p.y) * h[p.x*64 + l];
  }
  out[w*64 + l] = acc;
}

// ---------------- gate+out per hop (split-bf16 MFMA) ----------------
__global__ __launch_bounds__(256) void k_gateout(
    const float* __restrict__ hp, const float* __restrict__ hn,
    const ushort_t* __restrict__ Wgt_h, const ushort_t* __restrict__ Wot_h,
    const float* __restrict__ bg, const float* __restrict__ bo,
    float* __restrict__ h)
{
  __shared__ ushort_t Ag[64][264];  // hi [hp|hn] 0..127 | lo 128..255 | pad
  __shared__ ushort_t Bg[64][264];
  __shared__ ushort_t Ao[64][136];  // hi 0..63 | lo 64..127 | pad
  __shared__ ushort_t Bo[64][136];
  int t = threadIdx.x;
  int r0 = blockIdx.x * 64;
  const uint4* Wg4 = (const uint4*)Wgt_h;
  #pragma unroll
  for (int n = 0; n < 8; n++){
    int i = t + n*256; int row = i >> 5, kc = i & 31;
    *(uint4*)&Bg[row][kc*8] = Wg4[i];
  }
  const uint4* Wo4 = (const uint4*)Wot_h;
  #pragma unroll
  for (int n = 0; n < 4; n++){
    int i = t + n*256; int row = i >> 4, kc = i & 15;
    *(uint4*)&Bo[row][kc*8] = Wo4[i];
  }
  #pragma unroll
  for (int n = 0; n < 8; n++){
    int i = t + n*256; int row = i >> 5, g = i & 31;
    float4 vv = make_float4(0.f,0.f,0.f,0.f);
    int node = r0 + row;
    if (node < NN){
      if (g < 16) vv = *(const float4*)(hp + node*64 + g*4);
      else        vv = *(const float4*)(hn + node*64 + (g-16)*4);
    }
    float fv[4] = {vv.x,vv.y,vv.z,vv.w};
    us4 hi, lo;
    #pragma unroll
    for (int j = 0; j < 4; j++){
      ushort_t hh = f2bf(fv[j]); hi[j] = hh; lo[j] = f2bf(fv[j] - bf2f(hh));
    }
    *(us4*)&Ag[row][g*4] = hi;
    *(us4*)&Ag[row][128 + g*4] = lo;
  }
  __syncthreads();
  int l = t & 63, w = t >> 6;
  int lr = l & 15, lg = l >> 4;
  int wm = w >> 1, wn = w & 1;
  f32x4 z = {0.f,0.f,0.f,0.f};
  f32x4 acc[4] = {z,z,z,z};
  #pragma unroll
  for (int ks = 0; ks < 12; ks++){
    int aoff = (ks < 4) ? ks*32 : (ks < 8) ? 128 + (ks-4)*32 : (ks-8)*32;
    int boff = (ks < 8) ? (ks & 3)*32 : 128 + (ks-8)*32;
    bf8 a0 = *(const bf8*)&Ag[32*wm      + lr][aoff + 8*lg];
    bf8 a1 = *(const bf8*)&Ag[32*wm + 16 + lr][aoff + 8*lg];
    bf8 b0 = *(const bf8*)&Bg[32*wn      + lr][boff + 8*lg];
    bf8 b1 = *(const bf8*)&Bg[32*wn + 16 + lr][boff + 8*lg];
    acc[0] = MFMA(a0,b0,acc[0]);
    acc[1] = MFMA(a0,b1,acc[1]);
    acc[2] = MFMA(a1,b0,acc[2]);
    acc[3] = MFMA(a1,b1,acc[3]);
  }
  // gate epilogue -> h' staged into Ao (hi/lo)
  #pragma unroll
  for (int am = 0; am < 2; am++)
  #pragma unroll
  for (int bn = 0; bn < 2; bn++){
    f32x4 A = acc[am*2+bn];
    int col = 32*wn + 16*bn + lr;
    float bgv = bg[col];
    #pragma unroll
    for (int reg = 0; reg < 4; reg++){
      int row = 32*wm + 16*am + 4*lg + reg;
      float gv = sigm(A[reg] + bgv);
      float hpv = bf2f(Ag[row][col])      + bf2f(Ag[row][128+col]);
      float hnv = bf2f(Ag[row][64+col])   + bf2f(Ag[row][192+col]);
      float hv = gv*hpv + (1.f-gv)*hnv;
      ushort_t hh = f2bf(hv);
      Ao[row][col] = hh;
      Ao[row][64+col] = f2bf(hv - bf2f(hh));
    }
  }
  __syncthreads();
  f32x4 acc2[4] = {z,z,z,z};
  #pragma unroll
  for (int ks = 0; ks < 6; ks++){
    int aoff = (ks < 2) ? ks*32 : (ks < 4) ? 64 + (ks-2)*32 : (ks-4)*32;
    int boff = (ks < 4) ? (ks & 1)*32 : 64 + (ks-4)*32;
    bf8 a0 = *(const bf8*)&Ao[32*wm      + lr][aoff + 8*lg];
    bf8 a1 = *(const bf8*)&Ao[32*wm + 16 + lr][aoff + 8*lg];
    bf8 b0 = *(const bf8*)&Bo[32*wn      + lr][boff + 8*lg];
    bf8 b1 = *(const bf8*)&Bo[32*wn + 16 + lr][boff + 8*lg];
    acc2[0] = MFMA(a0,b0,acc2[0]);
    acc2[1] = MFMA(a0,b1,acc2[1]);
    acc2[2] = MFMA(a1,b0,acc2[2]);
    acc2[3] = MFMA(a1,b1,acc2[3]);
  }
  #pragma unroll
  for (int am = 0; am < 2; am++)
  #pragma unroll
  for (int bn = 0; bn < 2; bn++){
    f32x4 A = acc2[am*2+bn];
    int col = 32*wn + 16*bn + lr;
    float bov = bo[col];
    #pragma unroll
    for (int reg = 0; reg < 4; reg++){
      int row = 32*wm + 16*am + 4*lg + reg;
      if (r0 + row < NN) h[(r0+row)*64 + col] = tanh_f(A[reg] + bov);
    }
  }
}

// ---------------- edge MLP: feat[64 edges][288] bf16 @ W_e1, relu, @W_e2 ----------------
__global__ __launch_bounds__(256) void k_edge(
    const float* __restrict__ h, const int* __restrict__ u, const int* __restrict__ v,
    const float* __restrict__ ts, const ushort_t* __restrict__ Wt_e1,
    const float* __restrict__ b_e1, const float* __restrict__ W_e2,
    const float* __restrict__ b_e2, float* __restrict__ out)
{
  __shared__ ushort_t Al[64][296];
  __shared__ ushort_t Bl[64][296];
  __shared__ float part[2][64];
  int t = threadIdx.x;
  int e0 = blockIdx.x * 64;
  const uint4* W4 = (const uint4*)Wt_e1;
  #pragma unroll
  for (int n = 0; n < 9; n++){
    int i = t + n*256; int row = i / 36, kc = i - row*36;
    *(uint4*)&Bl[row][kc*8] = W4[i];
  }
  int el = t & 63, p = t >> 6;
  int eg = e0 + el;
  int ue = u[eg], ve = v[eg];
  const float* hu = h + ue*64 + p*16;
  const float* hv = h + ve*64 + p*16;
  #pragma unroll
  for (int half = 0; half < 2; half++){
    float4 ua = *(const float4*)(hu + half*8);
    float4 ub = *(const float4*)(hu + half*8 + 4);
    float4 va = *(const float4*)(hv + half*8);
    float4 vb = *(const float4*)(hv + half*8 + 4);
    float fu[8]  = {ua.x,ua.y,ua.z,ua.w,ub.x,ub.y,ub.z,ub.w};
    float fvv[8] = {va.x,va.y,va.z,va.w,vb.x,vb.y,vb.z,vb.w};
    us8 su, sv, sd, sp;
    #pragma unroll
    for (int j = 0; j < 8; j++){
      su[j] = f2bf(fu[j]); sv[j] = f2bf(fvv[j]);
      sd[j] = f2bf(fabsf(fu[j]-fvv[j])); sp[j] = f2bf(fu[j]*fvv[j]);
    }
    int d0 = p*16 + half*8;
    *(us8*)&Al[el][d0]       = su;
    *(us8*)&Al[el][64 + d0]  = sv;
    *(us8*)&Al[el][128 + d0] = sd;
    *(us8*)&Al[el][192 + d0] = sp;
  }
  if (p == 0){
    float tt = ts[eg];
    tt = fminf(fmaxf(tt, 0.f), 1.f);
    us8 ss, sc;
    #pragma unroll
    for (int k = 0; k < 8; k++){
      float ang = 3.14159265358979323846f * (float)(k+1) * tt;
      ss[k] = f2bf(__sinf(ang));
      sc[k] = f2bf(__cosf(ang));
    }
    *(us8*)&Al[el][256] = ss;
    *(us8*)&Al[el][264] = sc;
  } else if (p == 1){
    us8 zz = {0,0,0,0,0,0,0,0};
    *(us8*)&Al[el][272] = zz;
    *(us8*)&Al[el][280] = zz;
  }
  __syncthreads();
  int l = t & 63, w = t >> 6;
  int lr = l & 15, lg = l >> 4;
  int wm = w >> 1, wn = w & 1;
  f32x4 z4 = {0.f,0.f,0.f,0.f};
  f32x4 acc[4] = {z4,z4,z4,z4};
  #pragma unroll
  for (int ks = 0; ks < 9; ks++){
    int off = ks*32 + 8*lg;
    bf8 a0 = *(const bf8*)&Al[32*wm      + lr][off];
    bf8 a1 = *(const bf8*)&Al[32*wm + 16 + lr][off];
    bf8 b0 = *(const bf8*)&Bl[32*wn      + lr][off];
    bf8 b1 = *(const bf8*)&Bl[32*wn + 16 + lr][off];
    acc[0] = MFMA(a0,b0,acc[0]);
    acc[1] = MFMA(a0,b1,acc[1]);
    acc[2] = MFMA(a1,b0,acc[2]);
    acc[3] = MFMA(a1,b1,acc[3]);
  }
  int col0 = 32*wn + lr;
  int col1 = 32*wn + 16 + lr;
  float be0 = b_e1[col0], be1v = b_e1[col1];
  float w20 = W_e2[col0], w21 = W_e2[col1];
  #pragma unroll
  for (int am = 0; am < 2; am++){
    #pragma unroll
    for (int reg = 0; reg < 4; reg++){
      float h0 = fmaxf(acc[am*2+0][reg] + be0, 0.f);
      float h1 = fmaxf(acc[am*2+1][reg] + be1v, 0.f);
      float pt = h0*w20 + h1*w21;
      pt += __shfl_xor(pt, 1);
      pt += __shfl_xor(pt, 2);
      pt += __shfl_xor(pt, 4);
      pt += __shfl_xor(pt, 8);
      if (lr == 0){
        int row = 32*wm + 16*am + 4*lg + reg;
        part[wn][row] = pt;
      }
    }
  }
  __syncthreads();
  if (t < 64){
    out[e0 + t] = part[0][t] + part[1][t] + b_e2[0];
  }
}

extern "C" void kernel_launch(void* const* d_in, const int* in_sizes, int n_in,
                              void* d_out, int out_size, void* d_ws, size_t ws_size,
                              hipStream_t stream)
{
  (void)in_sizes; (void)n_in; (void)out_size; (void)ws_size;
  const float* x       = (const float*)d_in[0];
  const int*   pos_row = (const int*)d_in[1];
  const int*   pos_col = (const int*)d_in[2];
  const float* pos_val = (const float*)d_in[3];
  const int*   neg_row = (const int*)d_in[4];
  const int*   neg_col = (const int*)d_in[5];
  const float* neg_val = (const float*)d_in[6];
  const int*   u       = (const int*)d_in[7];
  const int*   v       = (const int*)d_in[8];
  const float* ets     = (const float*)d_in[9];
  const float* W_in    = (const float*)d_in[10];
  const float* b_in    = (const float*)d_in[11];
  const float* W_gate  = (const float*)d_in[12];
  const float* b_gate  = (const float*)d_in[13];
  const float* W_out   = (const float*)d_in[14];
  const float* b_out   = (const float*)d_in[15];
  const float* W_e1    = (const float*)d_in[16];
  const float* b_e1    = (const float*)d_in[17];
  const float* W_e2    = (const float*)d_in[18];
  const float* b_e2    = (const float*)d_in[19];
  float* out = (float*)d_out;

  char* wsb = (char*)d_ws;
  size_t off = 0;
  auto alloc = [&](size_t bytes)->char*{
    char* pp = wsb + off; off += (bytes + 255) & ~(size_t)255; return pp;
  };
  float*    h     = (float*)alloc((size_t)NN*64*4);
  float*    hp    = (float*)alloc((size_t)NN*64*4);
  float*    hn    = (float*)alloc((size_t)NN*64*4);
  uint2*    csr_p = (uint2*)alloc((size_t)NNZq*8);
  uint2*    csr_n = (uint2*)alloc((size_t)NNZq*8);
  int*      rp_p  = (int*)alloc((size_t)(NN+1)*4);
  int*      rp_n  = (int*)alloc((size_t)(NN+1)*4);
  int*      cur_p = (int*)alloc((size_t)NN*4);
  int*      cur_n = (int*)alloc((size_t)NN*4);
  int*      cnt_p = (int*)alloc((size_t)NN*4);
  int*      cnt_n = (int*)alloc((size_t)NN*4);
  int*      bs_p  = (int*)alloc(512*4);
  int*      bs_n  = (int*)alloc(512*4);
  ushort_t* Wt_in = (ushort_t*)alloc(64*512*2);
  ushort_t* Wgt   = (ushort_t*)alloc(2*64*256*2);
  ushort_t* Wot   = (ushort_t*)alloc(2*64*128*2);
  ushort_t* Wt_e1 = (ushort_t*)alloc(64*288*2);

  hipMemsetAsync(cnt_p, 0, (size_t)NN*4, stream);
  hipMemsetAsync(cnt_n, 0, (size_t)NN*4, stream);

  k_prep<<<64, 256, 0, stream>>>(W_in, W_gate, W_out, W_e1, Wt_in, Wgt, Wot, Wt_e1);
  k_embed<<<1563, 256, 0, stream>>>(x, Wt_in, b_in, h);

  k_hist<<<NNZq/256, 256, 0, stream>>>(pos_row, cnt_p);
  k_hist<<<NNZq/256, 256, 0, stream>>>(neg_row, cnt_n);
  int nb = (NN + 255)/256; // 391
  k_scan1<<<nb, 256, 0, stream>>>(cnt_p, rp_p, bs_p);
  k_scan1<<<nb, 256, 0, stream>>>(cnt_n, rp_n, bs_n);
  k_scan2<<<1, 512, 0, stream>>>(bs_p, nb);
  k_scan2<<<1, 512, 0, stream>>>(bs_n, nb);
  k_scan3<<<nb, 256, 0, stream>>>(rp_p, bs_p, cur_p);
  k_scan3<<<nb, 256, 0, stream>>>(rp_n, bs_n, cur_n);
  k_scatter<<<NNZq/256, 256, 0, stream>>>(pos_row, pos_col, pos_val, cur_p, csr_p);
  k_scatter<<<NNZq/256, 256, 0, stream>>>(neg_row, neg_col, neg_val, cur_n, csr_n);

  for (int hop = 0; hop < 2; hop++){
    k_spmm<<<NN/4, 256, 0, stream>>>(rp_p, csr_p, h, hp);
    k_spmm<<<NN/4, 256, 0, stream>>>(rp_n, csr_n, h, hn);
    k_gateout<<<1563, 256, 0, stream>>>(hp, hn,
        Wgt + (size_t)hop*16384, Wot + (size_t)hop*8192,
        b_gate + hop*64, b_out + hop*64, h);
  }
  k_edge<<<NE/64, 256, 0, stream>>>(h, u, v, ets, Wt_e1, b_e1, W_e2, b_e2, out);
}